// Round 1
// baseline (62.526 us; speedup 1.0000x reference)
//
#include <hip/hip_runtime.h>
#include <cstdint>

// GaussianImage Cholesky forward: N=512 gaussians -> (1,3,512,512) fp32 image.
// One block per 16x16 tile (32x32 grid, 256 threads). Phase 1: each chunk of
// 256 gaussians is tested against this tile's bounds and compacted (in index
// order, via ballot+prefix) into LDS with opacity premultiplied into features.
// Phase 2: each thread owns one pixel, accumulates 3 channels over the list.

#define IMG_W 512
#define IMG_H 512
#define TILE 16
#define TILES_X 32
#define TILES_Y 32
#define TPB 256

__global__ __launch_bounds__(TPB) void gsplat_render(
    const float* __restrict__ xyz,      // (N,2)
    const float* __restrict__ chol,     // (N,3)
    const float* __restrict__ feat,     // (N,3)
    const float* __restrict__ opac,     // (N,1)
    float* __restrict__ out,            // (3,512,512)
    int N)
{
    __shared__ float sg[TPB][8];   // compacted gaussians for current chunk
    __shared__ int   s_wcnt[4];    // per-wave accepted counts

    const int tid  = threadIdx.x;
    const int lane = tid & 63;
    const int wave = tid >> 6;
    const int bx   = blockIdx.x;   // tile x
    const int by   = blockIdx.y;   // tile y

    const int   px_i = bx * TILE + (tid & 15);
    const int   py_i = by * TILE + (tid >> 4);
    const float px   = (float)px_i;
    const float py   = (float)py_i;

    float a0 = 0.0f, a1 = 0.0f, a2 = 0.0f;

    for (int g0 = 0; g0 < N; g0 += TPB) {
        const int g = g0 + tid;
        bool accept = false;
        float ca = 0.f, cb = 0.f, cc = 0.f, gx = 0.f, gy = 0.f;
        float of0 = 0.f, of1 = 0.f, of2 = 0.f;

        if (g < N) {
            // per-gaussian derived quantities (cheap; recomputed per tile,
            // inputs are fully L2-resident: 18 KB total)
            const float mx = tanhf(xyz[2 * g]);
            const float my = tanhf(xyz[2 * g + 1]);
            const float l0 = chol[3 * g]     + 0.5f;
            const float l1 = chol[3 * g + 1];
            const float l2 = chol[3 * g + 2] + 0.5f;
            const float cxx = l0 * l0;
            const float cxy = l0 * l1;
            const float cyy = l1 * l1 + l2 * l2;
            const float det = cxx * cyy - cxy * cxy;   // = l0^2*l2^2 > 0
            const float inv = 1.0f / det;
            ca = cyy * inv;
            cb = -cxy * inv;
            cc = cxx * inv;
            gx = 0.5f * (float)IMG_W * (mx + 1.0f);
            gy = 0.5f * (float)IMG_H * (my + 1.0f);
            const float b  = 0.5f * (cxx + cyy);
            const float v1 = b + sqrtf(fmaxf(b * b - det, 0.1f));
            const float radius = ceilf(3.0f * sqrtf(v1));
            // (int) truncates toward zero, matching jnp astype(int32)
            const int tminx = min(max((int)((gx - radius) * (1.0f / TILE)), 0), TILES_X);
            const int tmaxx = min(max((int)((gx + radius) * (1.0f / TILE)) + 1, 0), TILES_X);
            const int tminy = min(max((int)((gy - radius) * (1.0f / TILE)), 0), TILES_Y);
            const int tmaxy = min(max((int)((gy + radius) * (1.0f / TILE)) + 1, 0), TILES_Y);
            accept = (bx >= tminx) && (bx < tmaxx) && (by >= tminy) && (by < tmaxy);
            if (accept) {
                const float op = opac[g];
                of0 = op * feat[3 * g];
                of1 = op * feat[3 * g + 1];
                of2 = op * feat[3 * g + 2];
            }
        }

        // ordered compaction: ballot prefix within wave, LDS counts across waves
        const unsigned long long bal = __ballot(accept);
        const int prefix = __popcll(bal & ((1ull << lane) - 1ull));
        if (lane == 0) s_wcnt[wave] = __popcll(bal);
        __syncthreads();
        int off = 0;
#pragma unroll
        for (int w2 = 0; w2 < 4; ++w2)
            if (w2 < wave) off += s_wcnt[w2];
        const int cnt = s_wcnt[0] + s_wcnt[1] + s_wcnt[2] + s_wcnt[3];
        if (accept) {
            const int idx = off + prefix;
            sg[idx][0] = ca;  sg[idx][1] = cb;  sg[idx][2] = cc;
            sg[idx][3] = gx;  sg[idx][4] = gy;
            sg[idx][5] = of0; sg[idx][6] = of1; sg[idx][7] = of2;
        }
        __syncthreads();

        // accumulate this chunk's gaussians (LDS broadcast reads — conflict-free)
        for (int i = 0; i < cnt; ++i) {
            const float dx = sg[i][3] - px;
            const float dy = sg[i][4] - py;
            const float sigma = 0.5f * sg[i][0] * dx * dx
                              + 0.5f * sg[i][2] * dy * dy
                              + sg[i][1] * dy * dx;
            const float w = __expf(-sigma);
            a0 += w * sg[i][5];
            a1 += w * sg[i][6];
            a2 += w * sg[i][7];
        }
        // next iteration's first __syncthreads() protects sg/s_wcnt reuse
    }

    const int base = py_i * IMG_W + px_i;
    out[base]                     = fminf(fmaxf(a0, 0.0f), 1.0f);
    out[IMG_H * IMG_W + base]     = fminf(fmaxf(a1, 0.0f), 1.0f);
    out[2 * IMG_H * IMG_W + base] = fminf(fmaxf(a2, 0.0f), 1.0f);
}

extern "C" void kernel_launch(void* const* d_in, const int* in_sizes, int n_in,
                              void* d_out, int out_size, void* d_ws, size_t ws_size,
                              hipStream_t stream) {
    const float* xyz  = (const float*)d_in[0];
    const float* chol = (const float*)d_in[1];
    const float* feat = (const float*)d_in[2];
    const float* opac = (const float*)d_in[3];
    float* out = (float*)d_out;
    const int N = in_sizes[0] / 2;

    dim3 grid(TILES_X, TILES_Y);
    gsplat_render<<<grid, TPB, 0, stream>>>(xyz, chol, feat, opac, out, N);
}

// Round 2
// 62.320 us; speedup vs baseline: 1.0033x; 1.0033x over previous
//
#include <hip/hip_runtime.h>
#include <cstdint>

// GaussianImage Cholesky forward: N=512 gaussians -> (1,3,512,512) fp32 image.
// One block per 16x16 tile (32x32 grid, 256 threads). Single pass: each thread
// tests 2 gaussians (tid, tid+256), fused ordered ballot-compaction into LDS
// (opacity premultiplied into features, ca/cc pre-halved), then each thread
// owns one pixel and accumulates 3 channels over the compacted list.

#define IMG_W 512
#define IMG_H 512
#define TILE 16
#define TILES_X 32
#define TILES_Y 32
#define TPB 256
#define MAXG 512

__device__ __forceinline__ float fast_tanh(float x) {
    x = fminf(fmaxf(x, -10.0f), 10.0f);
    const float e = __expf(2.0f * x);
    return (e - 1.0f) * __builtin_amdgcn_rcpf(e + 1.0f);
}

struct GParams {
    float ha, cb, hc, gx, gy, of0, of1, of2;
    bool accept;
};

__device__ __forceinline__ GParams setup_gaussian(
    int g, int bx, int by,
    const float* __restrict__ xyz, const float* __restrict__ chol,
    const float* __restrict__ feat, const float* __restrict__ opac)
{
    GParams r;
    const float2 p = ((const float2*)xyz)[g];
    const float mx = fast_tanh(p.x);
    const float my = fast_tanh(p.y);
    const float l0 = chol[3 * g]     + 0.5f;
    const float l1 = chol[3 * g + 1];
    const float l2 = chol[3 * g + 2] + 0.5f;
    const float cxx = l0 * l0;
    const float cxy = l0 * l1;
    const float cyy = l1 * l1 + l2 * l2;
    const float det = cxx * cyy - cxy * cxy;   // = l0^2*l2^2 > 0
    const float inv = __builtin_amdgcn_rcpf(det);
    r.ha = 0.5f * cyy * inv;
    r.cb = -cxy * inv;
    r.hc = 0.5f * cxx * inv;
    r.gx = 0.5f * (float)IMG_W * (mx + 1.0f);
    r.gy = 0.5f * (float)IMG_H * (my + 1.0f);
    const float b  = 0.5f * (cxx + cyy);
    const float v1 = b + sqrtf(fmaxf(b * b - det, 0.1f));
    const float radius = ceilf(3.0f * sqrtf(v1));
    // (int) truncates toward zero, matching jnp astype(int32)
    const int tminx = min(max((int)((r.gx - radius) * (1.0f / TILE)), 0), TILES_X);
    const int tmaxx = min(max((int)((r.gx + radius) * (1.0f / TILE)) + 1, 0), TILES_X);
    const int tminy = min(max((int)((r.gy - radius) * (1.0f / TILE)), 0), TILES_Y);
    const int tmaxy = min(max((int)((r.gy + radius) * (1.0f / TILE)) + 1, 0), TILES_Y);
    r.accept = (bx >= tminx) && (bx < tmaxx) && (by >= tminy) && (by < tmaxy);
    if (r.accept) {
        const float op = opac[g];
        r.of0 = op * feat[3 * g];
        r.of1 = op * feat[3 * g + 1];
        r.of2 = op * feat[3 * g + 2];
    } else {
        r.of0 = r.of1 = r.of2 = 0.0f;
    }
    return r;
}

__global__ __launch_bounds__(TPB) void gsplat_render(
    const float* __restrict__ xyz,      // (N,2)
    const float* __restrict__ chol,     // (N,3)
    const float* __restrict__ feat,     // (N,3)
    const float* __restrict__ opac,     // (N,1)
    float* __restrict__ out,            // (3,512,512)
    int N)
{
    __shared__ float sg[MAXG][8];   // compacted gaussians
    __shared__ int   s_wcnt[2][4];  // per-set, per-wave accepted counts

    const int tid  = threadIdx.x;
    const int lane = tid & 63;
    const int wave = tid >> 6;
    const int bx   = blockIdx.x;
    const int by   = blockIdx.y;

    // Set A: gaussian tid; Set B: gaussian tid+256 (index order preserved:
    // all A-accepted first, then B-accepted).
    const bool hasA = tid < N;
    const bool hasB = (tid + TPB) < N;
    GParams A, B;
    A.accept = B.accept = false;
    if (hasA) A = setup_gaussian(tid, bx, by, xyz, chol, feat, opac);
    if (hasB) B = setup_gaussian(tid + TPB, bx, by, xyz, chol, feat, opac);

    const unsigned long long balA = __ballot(A.accept);
    const unsigned long long balB = __ballot(B.accept);
    if (lane == 0) {
        s_wcnt[0][wave] = __popcll(balA);
        s_wcnt[1][wave] = __popcll(balB);
    }
    __syncthreads();

    int offA = 0, offB = 0, totalA = 0, totalB = 0;
#pragma unroll
    for (int w = 0; w < 4; ++w) {
        if (w < wave) { offA += s_wcnt[0][w]; offB += s_wcnt[1][w]; }
        totalA += s_wcnt[0][w];
        totalB += s_wcnt[1][w];
    }
    offB += totalA;
    const int cnt = totalA + totalB;

    const unsigned long long ltmask = (1ull << lane) - 1ull;
    if (A.accept) {
        const int i = offA + __popcll(balA & ltmask);
        sg[i][0] = A.ha;  sg[i][1] = A.cb;  sg[i][2] = A.hc;
        sg[i][3] = A.gx;  sg[i][4] = A.gy;
        sg[i][5] = A.of0; sg[i][6] = A.of1; sg[i][7] = A.of2;
    }
    if (B.accept) {
        const int i = offB + __popcll(balB & ltmask);
        sg[i][0] = B.ha;  sg[i][1] = B.cb;  sg[i][2] = B.hc;
        sg[i][3] = B.gx;  sg[i][4] = B.gy;
        sg[i][5] = B.of0; sg[i][6] = B.of1; sg[i][7] = B.of2;
    }
    __syncthreads();

    const int   px_i = bx * TILE + (tid & 15);
    const int   py_i = by * TILE + (tid >> 4);
    const float px   = (float)px_i;
    const float py   = (float)py_i;

    float a0 = 0.0f, a1 = 0.0f, a2 = 0.0f;
    for (int i = 0; i < cnt; ++i) {
        const float dx = sg[i][3] - px;
        const float dy = sg[i][4] - py;
        // sigma = 0.5*ca*dx^2 + 0.5*cc*dy^2 + cb*dx*dy  (ha/hc pre-halved)
        const float sigma = fmaf(sg[i][0] * dx, dx,
                            fmaf(sg[i][2] * dy, dy,
                                 sg[i][1] * dx * dy));
        const float w = __expf(-sigma);
        a0 = fmaf(w, sg[i][5], a0);
        a1 = fmaf(w, sg[i][6], a1);
        a2 = fmaf(w, sg[i][7], a2);
    }

    const int base = py_i * IMG_W + px_i;
    out[base]                     = fminf(fmaxf(a0, 0.0f), 1.0f);
    out[IMG_H * IMG_W + base]     = fminf(fmaxf(a1, 0.0f), 1.0f);
    out[2 * IMG_H * IMG_W + base] = fminf(fmaxf(a2, 0.0f), 1.0f);
}

extern "C" void kernel_launch(void* const* d_in, const int* in_sizes, int n_in,
                              void* d_out, int out_size, void* d_ws, size_t ws_size,
                              hipStream_t stream) {
    const float* xyz  = (const float*)d_in[0];
    const float* chol = (const float*)d_in[1];
    const float* feat = (const float*)d_in[2];
    const float* opac = (const float*)d_in[3];
    float* out = (float*)d_out;
    const int N = in_sizes[0] / 2;

    dim3 grid(TILES_X, TILES_Y);
    gsplat_render<<<grid, TPB, 0, stream>>>(xyz, chol, feat, opac, out, N);
}